// Round 2
// baseline (689.323 us; speedup 1.0000x reference)
//
#include <hip/hip_runtime.h>

#define HDIM 256
#define SPB  4   // samples per block == waves per block

// tanh jet: input pre-activation jet a[8] = (v, g0,g1,g2,g3, s0,s1,s2)
// output packed chunks A=(y, yg0, yg1, yg2), B=(yg3, ys0, ys1, ys2)
__device__ __forceinline__ void tanh_jet(const float a[8], float4& cA, float4& cB) {
    const float ty = tanhf(a[0]);
    const float t  = 1.f - ty * ty;
    const float m  = -2.f * ty * t;
    cA.x = ty;
    cA.y = t * a[1];
    cA.z = t * a[2];
    cA.w = t * a[3];
    cB.x = t * a[4];
    cB.y = t * a[5] + m * a[1] * a[1];
    cB.z = t * a[6] + m * a[2] * a[2];
    cB.w = t * a[7] + m * a[3] * a[3];
}

// One hidden layer (256 -> 256) for one wave's sample.
// yls: this wave's LDS region (512 float4 chunks, XOR-swizzled).
// If LAST, activated jets stay in outr[8] instead of LDS.
template<bool LAST>
__device__ __forceinline__ void hidden_layer(const float* __restrict__ W,
                                             const float* __restrict__ b,
                                             float4* __restrict__ yls,
                                             int l, int lx,
                                             float4* __restrict__ outr) {
    float acc[4][8];
#pragma unroll
    for (int r = 0; r < 4; ++r)
#pragma unroll
        for (int c = 0; c < 8; ++c) acc[r][c] = 0.f;

    const float* wp = W + 4 * l;
    __syncthreads();
#pragma unroll 4
    for (int k = 0; k < HDIM; ++k) {
        const int sw = (k >> 2) & 7;              // swizzle key, constant per 4 k's
        const float4 ya = yls[(2 * k) ^ sw];      // broadcast read: ch 0..3 of neuron k
        const float4 yb = yls[(2 * k + 1) ^ sw];  // ch 4..7
        const float4 wr = *(const float4*)(wp + k * HDIM);  // W[k][4l..4l+3]
        const float wf[4] = { wr.x, wr.y, wr.z, wr.w };
#pragma unroll
        for (int r = 0; r < 4; ++r) {
            acc[r][0] += wf[r] * ya.x;
            acc[r][1] += wf[r] * ya.y;
            acc[r][2] += wf[r] * ya.z;
            acc[r][3] += wf[r] * ya.w;
            acc[r][4] += wf[r] * yb.x;
            acc[r][5] += wf[r] * yb.y;
            acc[r][6] += wf[r] * yb.z;
            acc[r][7] += wf[r] * yb.w;
        }
    }
    __syncthreads();
    const float4 bv = *(const float4*)(b + 4 * l);
    const float bf[4] = { bv.x, bv.y, bv.z, bv.w };
#pragma unroll
    for (int r = 0; r < 4; ++r) {
        acc[r][0] += bf[r];
        float4 cA, cB;
        tanh_jet(acc[r], cA, cB);
        if (LAST) {
            outr[2 * r]     = cA;
            outr[2 * r + 1] = cB;
        } else {
            // chunk c = 8l + (2r+h); store at c ^ ((c>>3)&7) = 8l + ((2r+h)^(l&7))
            yls[8 * l + ((2 * r)     ^ lx)] = cA;
            yls[8 * l + ((2 * r + 1) ^ lx)] = cB;
        }
    }
}

__global__ __launch_bounds__(256)
void mlp_jet(const float* __restrict__ x,
             const float* __restrict__ W0, const float* __restrict__ b0,
             const float* __restrict__ W1, const float* __restrict__ b1,
             const float* __restrict__ W2, const float* __restrict__ b2,
             const float* __restrict__ W3, const float* __restrict__ b3,
             const float* __restrict__ Wo, const float* __restrict__ bo,
             float* __restrict__ out, int nB) {
    __shared__ float4 yl[SPB * 512];   // 32 KB: 8 KB per sample/wave
    const int tid = threadIdx.x;
    const int w   = tid >> 6;
    const int l   = tid & 63;
    const int lx  = l & 7;
    const int n   = blockIdx.x * SPB + w;
    float4* yls = yl + w * 512;

    // ---- layer 0: 4 -> 256 ----
    {
        const float4 xv4 = *(const float4*)(x + n * 4);
        const float xv[4] = { xv4.x, xv4.y, xv4.z, xv4.w };
        const float4 wr0 = *(const float4*)(W0 + 0 * HDIM + 4 * l);
        const float4 wr1 = *(const float4*)(W0 + 1 * HDIM + 4 * l);
        const float4 wr2 = *(const float4*)(W0 + 2 * HDIM + 4 * l);
        const float4 wr3 = *(const float4*)(W0 + 3 * HDIM + 4 * l);
        const float4 bv  = *(const float4*)(b0 + 4 * l);
        const float gr0[4] = { wr0.x, wr0.y, wr0.z, wr0.w };
        const float gr1[4] = { wr1.x, wr1.y, wr1.z, wr1.w };
        const float gr2[4] = { wr2.x, wr2.y, wr2.z, wr2.w };
        const float gr3[4] = { wr3.x, wr3.y, wr3.z, wr3.w };
        const float bfv[4] = { bv.x, bv.y, bv.z, bv.w };
#pragma unroll
        for (int r = 0; r < 4; ++r) {
            float a[8];
            a[1] = gr0[r];            // dU/dx_i = W0[i][j]
            a[2] = gr1[r];
            a[3] = gr2[r];
            a[4] = gr3[r];
            a[0] = xv[0] * a[1] + xv[1] * a[2] + xv[2] * a[3] + xv[3] * a[4] + bfv[r];
            a[5] = 0.f; a[6] = 0.f; a[7] = 0.f;
            float4 cA, cB;
            tanh_jet(a, cA, cB);
            yls[8 * l + ((2 * r)     ^ lx)] = cA;
            yls[8 * l + ((2 * r + 1) ^ lx)] = cB;
        }
    }

    float4 yr[8];
    hidden_layer<false>(W1, b1, yls, l, lx, yr);
    hidden_layer<false>(W2, b2, yls, l, lx, yr);
    hidden_layer<true >(W3, b3, yls, l, lx, yr);

    // ---- output layer: 256 -> 2, partials over this lane's 4 neurons ----
    const float4 woA = *(const float4*)(Wo + 8 * l);      // Wo[4l][0..1], Wo[4l+1][0..1]
    const float4 woB = *(const float4*)(Wo + 8 * l + 4);  // Wo[4l+2][0..1], Wo[4l+3][0..1]
    const float woL[4] = { woA.x, woA.z, woB.x, woB.z };  // output channel 0 (c)
    const float woH[4] = { woA.y, woA.w, woB.y, woB.w };  // output channel 1 (Fi)

    float p[2][8];
#pragma unroll
    for (int m = 0; m < 2; ++m)
#pragma unroll
        for (int c = 0; c < 8; ++c) p[m][c] = 0.f;

#pragma unroll
    for (int r = 0; r < 4; ++r) {
        const float ych[8] = { yr[2*r].x,   yr[2*r].y,   yr[2*r].z,   yr[2*r].w,
                               yr[2*r+1].x, yr[2*r+1].y, yr[2*r+1].z, yr[2*r+1].w };
#pragma unroll
        for (int c = 0; c < 8; ++c) {
            p[0][c] += woL[r] * ych[c];
            p[1][c] += woH[r] * ych[c];
        }
    }

    // wave-wide butterfly reduction of 16 partials
#pragma unroll
    for (int off = 32; off > 0; off >>= 1)
#pragma unroll
        for (int m = 0; m < 2; ++m)
#pragma unroll
            for (int c = 0; c < 8; ++c)
                p[m][c] += __shfl_xor(p[m][c], off);

    if (l == 0) {
        const float c0  = p[0][0] + bo[0];   // bias only on value channel
        const float Fi  = p[1][0] + bo[1];
        const float cg0 = p[0][1], cg1 = p[0][2], cg2 = p[0][3];
        const float ct  = p[0][4];           // dc/dx_3 (TDIM)
        const float fg0 = p[1][1], fg1 = p[1][2], fg2 = p[1][3];
        const float trHc  = p[0][5] + p[0][6] + p[0][7];
        const float fiLap = p[1][5] + p[1][6] + p[1][7];
        const float jd = -trHc
                         - (cg0 * fg0 + cg1 * fg1 + cg2 * fg2 + c0 * fiLap)
                         + 0.1f * (cg0 + cg1 + cg2);
        out[0 * nB + n]         = c0;
        out[1 * nB + n]         = ct;
        out[2 * nB + 3 * n + 0] = cg0;
        out[2 * nB + 3 * n + 1] = cg1;
        out[2 * nB + 3 * n + 2] = cg2;
        out[5 * nB + n]         = Fi;
        out[6 * nB + 3 * n + 0] = fg0;
        out[6 * nB + 3 * n + 1] = fg1;
        out[6 * nB + 3 * n + 2] = fg2;
        out[9 * nB + n]         = fiLap;
        out[10 * nB + n]        = jd;
    }
}

extern "C" void kernel_launch(void* const* d_in, const int* in_sizes, int n_in,
                              void* d_out, int out_size, void* d_ws, size_t ws_size,
                              hipStream_t stream) {
    const float* x  = (const float*)d_in[0];
    const float* W0 = (const float*)d_in[1];
    const float* b0 = (const float*)d_in[2];
    const float* W1 = (const float*)d_in[3];
    const float* b1 = (const float*)d_in[4];
    const float* W2 = (const float*)d_in[5];
    const float* b2 = (const float*)d_in[6];
    const float* W3 = (const float*)d_in[7];
    const float* b3 = (const float*)d_in[8];
    const float* Wo = (const float*)d_in[9];
    const float* bo = (const float*)d_in[10];
    float* out = (float*)d_out;

    const int nB = in_sizes[0] / 4;          // 16384
    dim3 grid(nB / SPB), block(256);
    hipLaunchKernelGGL(mlp_jet, grid, block, 0, stream,
                       x, W0, b0, W1, b1, W2, b2, W3, b3, Wo, bo, out, nB);
}

// Round 3
// 191.902 us; speedup vs baseline: 3.5921x; 3.5921x over previous
//
#include <hip/hip_runtime.h>

#define HDIM  256
#define YP    264              // padded Y row length in bf16 elems (528 B = 33*16B)
#define SPBM  8                // samples per block
#define MROWS (SPBM * 8)       // 64 jet rows per block

typedef unsigned short u16;
typedef __attribute__((ext_vector_type(8))) short  short8;   // 8 bf16 (4 VGPRs)
typedef __attribute__((ext_vector_type(4))) float  f32x4;    // MFMA acc

__device__ __forceinline__ float bf2f(u16 u) {
    union { unsigned int i; float f; } v; v.i = ((unsigned int)u) << 16; return v.f;
}
__device__ __forceinline__ u16 f2bf(float f) {
    union { float f; unsigned int u; } v; v.f = f;
    unsigned int r = v.u + 0x7fffu + ((v.u >> 16) & 1u);   // RNE
    return (u16)(r >> 16);
}

// ---- prepass: W[k][n] f32  ->  Wt[n][k] bf16, for W1,W2,W3 into d_ws ----
__global__ __launch_bounds__(256)
void transpose_w(const float* __restrict__ W1, const float* __restrict__ W2,
                 const float* __restrict__ W3, u16* __restrict__ ws) {
    const int idx   = blockIdx.x * 256 + threadIdx.x;   // 3*65536 total
    const int which = idx >> 16;
    const int rem   = idx & 65535;
    const int k = rem >> 8, n = rem & 255;
    const float* W = (which == 0) ? W1 : ((which == 1) ? W2 : W3);
    ws[which * 65536 + n * 256 + k] = f2bf(W[k * 256 + n]);
}

// ---- one hidden layer: Y(LDS, 64x256 bf16 jets) @ W(256x256) -> jets, in place ----
// C/D layout: col=lane&15, row=(lane>>4)*4+reg.  A: A[m=lane&15][k=8*(lane>>4)+j].
// Channel rows per sample: 0=v 1=g0 2=g1 3=g2 | 4=g3 5=s0 6=s1 7=s2  -> lane L pairs L^16.
__device__ __forceinline__ void hidden_layer_mfma(u16* __restrict__ Y,
                                                  const u16* __restrict__ Wt,
                                                  const float* __restrict__ b,
                                                  int l, int wv) {
    const int lm   = l & 15;          // row (A) / col (B,C) within tile
    const int lk8  = (l >> 4) * 8;    // k sub-offset
    const int nbase = wv * 64;

    f32x4 acc[4][4];
#pragma unroll
    for (int mt = 0; mt < 4; ++mt)
#pragma unroll
        for (int nt = 0; nt < 4; ++nt) acc[mt][nt] = (f32x4){0.f, 0.f, 0.f, 0.f};

#pragma unroll
    for (int ks = 0; ks < 8; ++ks) {
        const int kk = ks * 32 + lk8;
        short8 a[4], bf[4];
#pragma unroll
        for (int mt = 0; mt < 4; ++mt)
            a[mt] = *(const short8*)(Y + (mt * 16 + lm) * YP + kk);
#pragma unroll
        for (int nt = 0; nt < 4; ++nt)
            bf[nt] = *(const short8*)(Wt + ((nbase + nt * 16 + lm) << 8) + kk);
#pragma unroll
        for (int mt = 0; mt < 4; ++mt)
#pragma unroll
            for (int nt = 0; nt < 4; ++nt)
                acc[mt][nt] = __builtin_amdgcn_mfma_f32_16x16x32_bf16(
                    a[mt], bf[nt], acc[mt][nt], 0, 0, 0);
    }

    float bias[4];
#pragma unroll
    for (int nt = 0; nt < 4; ++nt) bias[nt] = b[nbase + nt * 16 + lm];

    __syncthreads();   // all waves done READING Y before anyone overwrites it

    const int hi = (l >> 4) & 1;      // 0: rows v,g0,g1,g2   1: rows g3,s0,s1,s2
#pragma unroll
    for (int mt = 0; mt < 4; ++mt) {
        const int r0 = mt * 16 + (l >> 4) * 4;
#pragma unroll
        for (int nt = 0; nt < 4; ++nt) {
            const f32x4 u = acc[mt][nt];
            const float ty  = tanhf(u[0] + bias[nt]);  // meaningful on hi==0 lanes
            const float typ = __shfl_xor(ty,  16);
            const float p1  = __shfl_xor(u[1], 16);    // partner's g0,g1,g2 pre-acts
            const float p2  = __shfl_xor(u[2], 16);
            const float p3  = __shfl_xor(u[3], 16);
            const float tv = hi ? typ : ty;
            const float t  = 1.f - tv * tv;
            const float m  = -2.f * tv * t;
            const float o0 = hi ? t * u[0] : tv;                    // g3 | v
            const float o1 = t * u[1] + (hi ? m * p1 * p1 : 0.f);   // s0 | g0
            const float o2 = t * u[2] + (hi ? m * p2 * p2 : 0.f);   // s1 | g1
            const float o3 = t * u[3] + (hi ? m * p3 * p3 : 0.f);   // s2 | g2
            const int n = nbase + nt * 16 + lm;
            Y[(r0 + 0) * YP + n] = f2bf(o0);
            Y[(r0 + 1) * YP + n] = f2bf(o1);
            Y[(r0 + 2) * YP + n] = f2bf(o2);
            Y[(r0 + 3) * YP + n] = f2bf(o3);
        }
    }
    __syncthreads();
}

__global__ __launch_bounds__(256, 4)
void mlp_jet_mfma(const float* __restrict__ x,
                  const float* __restrict__ W0, const float* __restrict__ b0,
                  const float* __restrict__ b1, const float* __restrict__ b2,
                  const float* __restrict__ b3,
                  const float* __restrict__ Wo, const float* __restrict__ bo,
                  const u16* __restrict__ Wt,   // 3 x [n][k] bf16
                  float* __restrict__ out, int nB) {
    __shared__ __align__(16) u16 Y[MROWS * YP];      // 33 KB jet activations
    __shared__ float4 xs4[SPBM];
    __shared__ float  part[4][MROWS];

    const int tid = threadIdx.x;
    const int wv  = tid >> 6;
    const int l   = tid & 63;
    const int n0  = blockIdx.x * SPBM;

    // ---- layer 0: 4 -> 256, VALU ----
    if (tid < SPBM) xs4[tid] = *(const float4*)(x + (n0 + tid) * 4);
    __syncthreads();
    {
        const int n = tid;                                  // neuron column
        const float w0 = W0[0 * HDIM + n], w1 = W0[1 * HDIM + n];
        const float w2 = W0[2 * HDIM + n], w3 = W0[3 * HDIM + n];
        const float bb = b0[n];
#pragma unroll
        for (int s = 0; s < SPBM; ++s) {
            const float4 xv = xs4[s];
            const float u  = xv.x * w0 + xv.y * w1 + xv.z * w2 + xv.w * w3 + bb;
            const float ty = tanhf(u);
            const float t  = 1.f - ty * ty;
            const float m  = -2.f * ty * t;
            u16* yr = Y + (8 * s) * YP + n;
            yr[0 * YP] = f2bf(ty);
            yr[1 * YP] = f2bf(t * w0);
            yr[2 * YP] = f2bf(t * w1);
            yr[3 * YP] = f2bf(t * w2);
            yr[4 * YP] = f2bf(t * w3);
            yr[5 * YP] = f2bf(m * w0 * w0);
            yr[6 * YP] = f2bf(m * w1 * w1);
            yr[7 * YP] = f2bf(m * w2 * w2);
        }
    }
    __syncthreads();

    // ---- 3 hidden layers on the matrix pipe ----
    hidden_layer_mfma(Y, Wt + 0 * 65536, b1, l, wv);
    hidden_layer_mfma(Y, Wt + 1 * 65536, b2, l, wv);
    hidden_layer_mfma(Y, Wt + 2 * 65536, b3, l, wv);

    // ---- output head: 256 -> 2 per jet row, VALU ----
    {
        const int oc = wv & 1;         // output column
        const int kb = (wv >> 1) * 128;  // K half
        float pacc = 0.f;
#pragma unroll
        for (int c = 0; c < 16; ++c) {
            const short8 yv = *(const short8*)(Y + l * YP + kb + c * 8);
#pragma unroll
            for (int j = 0; j < 8; ++j)
                pacc += bf2f((u16)yv[j]) * Wo[(kb + c * 8 + j) * 2 + oc];
        }
        part[wv][l] = pacc;
    }
    __syncthreads();

    if (tid < SPBM) {
        const int s = tid;
        float q0[8], q1[8];
#pragma unroll
        for (int ch = 0; ch < 8; ++ch) {
            const int m = 8 * s + ch;
            q0[ch] = part[0][m] + part[2][m];   // dot(Y[m], Wo[:,0])
            q1[ch] = part[1][m] + part[3][m];   // dot(Y[m], Wo[:,1])
        }
        const float c0  = q0[0] + bo[0];
        const float Fi  = q1[0] + bo[1];
        const float cg0 = q0[1], cg1 = q0[2], cg2 = q0[3];
        const float ct  = q0[4];                 // dc/dx_3 (TDIM)
        const float fg0 = q1[1], fg1 = q1[2], fg2 = q1[3];
        const float trHc  = q0[5] + q0[6] + q0[7];
        const float fiLap = q1[5] + q1[6] + q1[7];
        const float jd = -trHc
                         - (cg0 * fg0 + cg1 * fg1 + cg2 * fg2 + c0 * fiLap)
                         + 0.1f * (cg0 + cg1 + cg2);
        const int n = n0 + s;
        out[0 * nB + n]         = c0;
        out[1 * nB + n]         = ct;
        out[2 * nB + 3 * n + 0] = cg0;
        out[2 * nB + 3 * n + 1] = cg1;
        out[2 * nB + 3 * n + 2] = cg2;
        out[5 * nB + n]         = Fi;
        out[6 * nB + 3 * n + 0] = fg0;
        out[6 * nB + 3 * n + 1] = fg1;
        out[6 * nB + 3 * n + 2] = fg2;
        out[9 * nB + n]         = fiLap;
        out[10 * nB + n]        = jd;
    }
}

extern "C" void kernel_launch(void* const* d_in, const int* in_sizes, int n_in,
                              void* d_out, int out_size, void* d_ws, size_t ws_size,
                              hipStream_t stream) {
    const float* x  = (const float*)d_in[0];
    const float* W0 = (const float*)d_in[1];
    const float* b0 = (const float*)d_in[2];
    const float* W1 = (const float*)d_in[3];
    const float* b1 = (const float*)d_in[4];
    const float* W2 = (const float*)d_in[5];
    const float* b2 = (const float*)d_in[6];
    const float* W3 = (const float*)d_in[7];
    const float* b3 = (const float*)d_in[8];
    const float* Wo = (const float*)d_in[9];
    const float* bo = (const float*)d_in[10];
    float* out = (float*)d_out;
    u16*   Wt  = (u16*)d_ws;                 // 3 * 65536 bf16 = 384 KB

    const int nB = in_sizes[0] / 4;          // 16384

    hipLaunchKernelGGL(transpose_w, dim3(3 * 65536 / 256), dim3(256), 0, stream,
                       W1, W2, W3, Wt);
    hipLaunchKernelGGL(mlp_jet_mfma, dim3(nB / SPBM), dim3(256), 0, stream,
                       x, W0, b0, b1, b2, b3, Wo, bo, Wt, out, nB);
}

// Round 4
// 188.798 us; speedup vs baseline: 3.6511x; 1.0164x over previous
//
#include <hip/hip_runtime.h>

#define HDIM  256
#define YP    264              // padded Y row length in bf16 elems
#define SPBM  8                // samples per block
#define MROWS (SPBM * 8)       // 64 jet rows per block

typedef unsigned short u16;
typedef __attribute__((ext_vector_type(8))) short  short8;   // 8 bf16 (4 VGPRs)
typedef __attribute__((ext_vector_type(4))) float  f32x4;    // MFMA acc

__device__ __forceinline__ float bf2f(u16 u) {
    union { unsigned int i; float f; } v; v.i = ((unsigned int)u) << 16; return v.f;
}
// cheap round-half-up bf16 (2 VALU instr); fine vs 3% abs threshold
__device__ __forceinline__ u16 f2bf(float f) {
    union { float f; unsigned int u; } v; v.f = f;
    return (u16)((v.u + 0x8000u) >> 16);
}
// proper RNE, used once in prepass for weights
__device__ __forceinline__ u16 f2bf_rne(float f) {
    union { float f; unsigned int u; } v; v.f = f;
    unsigned int r = v.u + 0x7fffu + ((v.u >> 16) & 1u);
    return (u16)(r >> 16);
}
// tanh(x) = 1 - 2/(e^{2x}+1) on raw v_exp_f32 / v_rcp_f32 (~4 instr, NaN-free)
__device__ __forceinline__ float fast_tanh(float x) {
    const float e = __builtin_amdgcn_exp2f(x * 2.885390081777927f); // e^{2x}
    const float r = __builtin_amdgcn_rcpf(e + 1.f);
    return 1.f - 2.f * r;
}

// ---- prepass: LDS-tiled transpose W[k][n] f32 -> Wt[n][k] bf16 (W1,W2,W3),
// ---- plus Wo[k][2] -> Wob[2][256] bf16 at ws + 3*65536.
__global__ __launch_bounds__(256)
void prep_w(const float* __restrict__ W1, const float* __restrict__ W2,
            const float* __restrict__ W3, const float* __restrict__ Wo,
            u16* __restrict__ ws) {
    const int bid = blockIdx.x;
    const int tid = threadIdx.x;
    if (bid == 48) {
#pragma unroll
        for (int oc = 0; oc < 2; ++oc)
            ws[3 * 65536 + oc * 256 + tid] = f2bf_rne(Wo[tid * 2 + oc]);
        return;
    }
    const int which = bid >> 4;
    const int tile  = bid & 15;
    const int k0 = (tile >> 2) * 64, n0 = (tile & 3) * 64;
    const float* W = (which == 0) ? W1 : ((which == 1) ? W2 : W3);
    __shared__ float T[64][65];
    const int rk = tid >> 4;          // 0..15
    const int rn = (tid & 15) * 4;    // 0..60
#pragma unroll
    for (int rep = 0; rep < 4; ++rep) {
        const float4 v = *(const float4*)(W + (k0 + rep * 16 + rk) * 256 + n0 + rn);
        T[rep * 16 + rk][rn + 0] = v.x;
        T[rep * 16 + rk][rn + 1] = v.y;
        T[rep * 16 + rk][rn + 2] = v.z;
        T[rep * 16 + rk][rn + 3] = v.w;
    }
    __syncthreads();
    const int wn = tid >> 4;
    const int wk = (tid & 15) * 4;
#pragma unroll
    for (int rep = 0; rep < 4; ++rep) {
        const int nl = rep * 16 + wn;
        ushort4 o;
        o.x = f2bf_rne(T[wk + 0][nl]);
        o.y = f2bf_rne(T[wk + 1][nl]);
        o.z = f2bf_rne(T[wk + 2][nl]);
        o.w = f2bf_rne(T[wk + 3][nl]);
        *(ushort4*)(ws + which * 65536 + (n0 + nl) * 256 + k0 + wk) = o;
    }
}

// ---- one hidden layer: Y(LDS, 64x256 bf16 jets) @ W(256x256) -> jets, in place ----
// C/D: col=lane&15, row=(lane>>4)*4+reg.  A: A[m=lane&15][k=8*(lane>>4)+j].
// Channel rows per sample: 0=v 1=g0 2=g1 3=g2 | 4=g3 5=s0 6=s1 7=s2 -> lane L pairs L^16.
__device__ __forceinline__ void hidden_layer_mfma(u16* __restrict__ Y,
                                                  const u16* __restrict__ Wt,
                                                  const float* __restrict__ b,
                                                  int l, int wv) {
    const int lm    = l & 15;
    const int lk8   = (l >> 4) * 8;
    const int nbase = wv * 64;

    f32x4 acc[4][4];
#pragma unroll
    for (int mt = 0; mt < 4; ++mt)
#pragma unroll
        for (int nt = 0; nt < 4; ++nt) acc[mt][nt] = (f32x4){0.f, 0.f, 0.f, 0.f};

#pragma unroll
    for (int ks = 0; ks < 8; ++ks) {
        const int kk = ks * 32 + lk8;
        short8 a[4], bf[4];
#pragma unroll
        for (int mt = 0; mt < 4; ++mt)
            a[mt] = *(const short8*)(Y + (mt * 16 + lm) * YP + kk);
#pragma unroll
        for (int nt = 0; nt < 4; ++nt)
            bf[nt] = *(const short8*)(Wt + ((nbase + nt * 16 + lm) << 8) + kk);
#pragma unroll
        for (int mt = 0; mt < 4; ++mt)
#pragma unroll
            for (int nt = 0; nt < 4; ++nt)
                acc[mt][nt] = __builtin_amdgcn_mfma_f32_16x16x32_bf16(
                    a[mt], bf[nt], acc[mt][nt], 0, 0, 0);
    }

    float bias[4];
#pragma unroll
    for (int nt = 0; nt < 4; ++nt) bias[nt] = b[nbase + nt * 16 + lm];

    __syncthreads();   // all waves done READING Y before anyone overwrites it

    const int hi = (l >> 4) & 1;      // 0: rows v,g0,g1,g2   1: rows g3,s0,s1,s2
#pragma unroll
    for (int mt = 0; mt < 4; ++mt) {
        const int r0 = mt * 16 + (l >> 4) * 4;
#pragma unroll
        for (int nt = 0; nt < 4; ++nt) {
            const f32x4 u = acc[mt][nt];
            const float ty  = fast_tanh(u[0] + bias[nt]);  // meaningful on hi==0 lanes
            const float typ = __shfl_xor(ty,  16);
            const float p1  = __shfl_xor(u[1], 16);        // partner's g preacts
            const float p2  = __shfl_xor(u[2], 16);
            const float p3  = __shfl_xor(u[3], 16);
            const float tv = hi ? typ : ty;
            const float t  = 1.f - tv * tv;
            const float m  = -2.f * tv * t;
            const float o0 = hi ? t * u[0] : tv;                    // g3 | v
            const float o1 = t * u[1] + (hi ? m * p1 * p1 : 0.f);   // s0 | g0
            const float o2 = t * u[2] + (hi ? m * p2 * p2 : 0.f);   // s1 | g1
            const float o3 = t * u[3] + (hi ? m * p3 * p3 : 0.f);   // s2 | g2
            const int n = nbase + nt * 16 + lm;
            Y[(r0 + 0) * YP + n] = f2bf(o0);
            Y[(r0 + 1) * YP + n] = f2bf(o1);
            Y[(r0 + 2) * YP + n] = f2bf(o2);
            Y[(r0 + 3) * YP + n] = f2bf(o3);
        }
    }
    __syncthreads();
}

__global__ __launch_bounds__(256, 3)
void mlp_jet_mfma(const float* __restrict__ x,
                  const float* __restrict__ W0, const float* __restrict__ b0,
                  const float* __restrict__ b1, const float* __restrict__ b2,
                  const float* __restrict__ b3, const float* __restrict__ bo,
                  const u16* __restrict__ Wt,   // 3 x Wt[n][k] bf16, + Wob[2][256]
                  float* __restrict__ out, int nB) {
    __shared__ __align__(16) u16 Y[MROWS * YP];
    __shared__ float4 xs4[SPBM];
    __shared__ float  part[MROWS][2];

    const int tid = threadIdx.x;
    const int wv  = tid >> 6;
    const int l   = tid & 63;
    const int lm  = l & 15;
    const int lk8 = (l >> 4) * 8;
    const int n0  = blockIdx.x * SPBM;

    // ---- layer 0: 4 -> 256, VALU ----
    if (tid < SPBM) xs4[tid] = *(const float4*)(x + (n0 + tid) * 4);
    __syncthreads();
    {
        const int n = tid;
        const float w0 = W0[0 * HDIM + n], w1 = W0[1 * HDIM + n];
        const float w2 = W0[2 * HDIM + n], w3 = W0[3 * HDIM + n];
        const float bb = b0[n];
#pragma unroll
        for (int s = 0; s < SPBM; ++s) {
            const float4 xv = xs4[s];
            const float u  = xv.x * w0 + xv.y * w1 + xv.z * w2 + xv.w * w3 + bb;
            const float ty = fast_tanh(u);
            const float t  = 1.f - ty * ty;
            const float m  = -2.f * ty * t;
            u16* yr = Y + (8 * s) * YP + n;
            yr[0 * YP] = f2bf(ty);
            yr[1 * YP] = f2bf(t * w0);
            yr[2 * YP] = f2bf(t * w1);
            yr[3 * YP] = f2bf(t * w2);
            yr[4 * YP] = f2bf(t * w3);
            yr[5 * YP] = f2bf(m * w0 * w0);
            yr[6 * YP] = f2bf(m * w1 * w1);
            yr[7 * YP] = f2bf(m * w2 * w2);
        }
    }
    __syncthreads();

    // ---- 3 hidden layers on the matrix pipe ----
    hidden_layer_mfma(Y, Wt + 0 * 65536, b1, l, wv);
    hidden_layer_mfma(Y, Wt + 1 * 65536, b2, l, wv);
    hidden_layer_mfma(Y, Wt + 2 * 65536, b3, l, wv);

    // ---- output head on MFMA: wave wv takes rows wv*16..wv*16+15 ----
    {
        const u16* wob = Wt + 3 * 65536;
        f32x4 h = (f32x4){0.f, 0.f, 0.f, 0.f};
#pragma unroll
        for (int ks = 0; ks < 8; ++ks) {
            const int kk = ks * 32 + lk8;
            const short8 a = *(const short8*)(Y + (wv * 16 + lm) * YP + kk);
            short8 bfr = (short8){0,0,0,0,0,0,0,0};
            if (lm < 2) bfr = *(const short8*)(wob + lm * 256 + kk);
            h = __builtin_amdgcn_mfma_f32_16x16x32_bf16(a, bfr, h, 0, 0, 0);
        }
        if (lm < 2) {
#pragma unroll
            for (int r = 0; r < 4; ++r)
                part[wv * 16 + (l >> 4) * 4 + r][lm] = h[r];
        }
    }
    __syncthreads();

    if (tid < SPBM) {
        const int s = tid;
        float q0[8], q1[8];
#pragma unroll
        for (int ch = 0; ch < 8; ++ch) {
            q0[ch] = part[8 * s + ch][0];
            q1[ch] = part[8 * s + ch][1];
        }
        const float c0  = q0[0] + bo[0];
        const float Fi  = q1[0] + bo[1];
        const float cg0 = q0[1], cg1 = q0[2], cg2 = q0[3];
        const float ct  = q0[4];                 // dc/dx_3 (TDIM)
        const float fg0 = q1[1], fg1 = q1[2], fg2 = q1[3];
        const float trHc  = q0[5] + q0[6] + q0[7];
        const float fiLap = q1[5] + q1[6] + q1[7];
        const float jd = -trHc
                         - (cg0 * fg0 + cg1 * fg1 + cg2 * fg2 + c0 * fiLap)
                         + 0.1f * (cg0 + cg1 + cg2);
        const int n = n0 + s;
        out[0 * nB + n]         = c0;
        out[1 * nB + n]         = ct;
        out[2 * nB + 3 * n + 0] = cg0;
        out[2 * nB + 3 * n + 1] = cg1;
        out[2 * nB + 3 * n + 2] = cg2;
        out[5 * nB + n]         = Fi;
        out[6 * nB + 3 * n + 0] = fg0;
        out[6 * nB + 3 * n + 1] = fg1;
        out[6 * nB + 3 * n + 2] = fg2;
        out[9 * nB + n]         = fiLap;
        out[10 * nB + n]        = jd;
    }
}

extern "C" void kernel_launch(void* const* d_in, const int* in_sizes, int n_in,
                              void* d_out, int out_size, void* d_ws, size_t ws_size,
                              hipStream_t stream) {
    const float* x  = (const float*)d_in[0];
    const float* W0 = (const float*)d_in[1];
    const float* b0 = (const float*)d_in[2];
    const float* W1 = (const float*)d_in[3];
    const float* b1 = (const float*)d_in[4];
    const float* W2 = (const float*)d_in[5];
    const float* b2 = (const float*)d_in[6];
    const float* W3 = (const float*)d_in[7];
    const float* b3 = (const float*)d_in[8];
    const float* Wo = (const float*)d_in[9];
    const float* bo = (const float*)d_in[10];
    float* out = (float*)d_out;
    u16*   Wt  = (u16*)d_ws;                 // 3*65536 + 512 bf16 ≈ 385 KB

    const int nB = in_sizes[0] / 4;          // 16384

    hipLaunchKernelGGL(prep_w, dim3(49), dim3(256), 0, stream, W1, W2, W3, Wo, Wt);
    hipLaunchKernelGGL(mlp_jet_mfma, dim3(nB / SPBM), dim3(256), 0, stream,
                       x, W0, b0, b1, b2, b3, bo, Wt, out, nB);
}